// Round 4
// baseline (28.600 us; speedup 1.0000x reference)
//
#include <hip/hip_runtime.h>

// x: [B=4, C=8, H=512, W=512] f32 -> out: [B, C, 3969, 16, 16] f32
// BLOCK=(16,16), STRIDE=(8,8), nbh=nbw=63
constexpr int H = 512, W = 512;
constexpr int BH = 16, BW = 16, SH = 8, SW = 8;
constexpr int NBH = (H - BH) / SH + 1;   // 63
constexpr int NBW = (W - BW) / SW + 1;   // 63
constexpr int NP  = NBH * NBW;           // 3969
constexpr int W4  = W / 4;               // 128 float4 per input row
constexpr int HW4 = H * W / 4;           // 65536 float4 per (b,c) image
constexpr int BC      = 4 * 8;           // 32 (b,c) images
constexpr int NBLOCKS = BC * NBH;        // 2016 blocks, one per (bc, pr) strip
constexpr int CHUNK   = NBLOCKS / 8;     // 252 blocks per XCD (2016 % 8 == 0)
constexpr int S_STRIP = NBW * BH * (BW / 4); // 4032 float4 per strip
constexpr int NT      = 576;             // 9 waves; 4032/576 = 7 exact iters
constexpr int NITER   = S_STRIP / NT;    // 7
// stride-576 invariants: 576%4==0 -> q const; (576>>2)%16==0 -> i const;
// pc advances by 576>>6 = 9 per iteration.

typedef float f32x4 __attribute__((ext_vector_type(4)));

__global__ __launch_bounds__(NT) void block_extract_strip(
        const f32x4* __restrict__ x4, f32x4* __restrict__ out4) {
    int bid = blockIdx.x;
    // bijective XCD swizzle: consecutive swz (adjacent pr strips, shared rows)
    // land on the same XCD -> vertical-overlap reads hit that XCD's L2.
    int swz = (bid & 7) * CHUNK + (bid >> 3);
    int bc  = swz / NBH;              // one div per block (magic-mul)
    int pr  = swz - bc * NBH;

    int s  = threadIdx.x;            // initial flat index, 0..575
    int q  = s & 3;                  // float4 within patch row (const)
    int i  = (s >> 2) & 15;          // patch row (const)
    int pc = s >> 6;                 // patch column start (advances +9)

    const f32x4* __restrict__ src =
        x4 + bc * HW4 + (pr * SH + i) * W4 + pc * (SW / 4) + q;
    f32x4* __restrict__ dst =
        out4 + (size_t)(bc * NP + pr * NBW) * (BH * BW / 4) + s;

#pragma unroll
    for (int k = 0; k < NITER; ++k) {
        f32x4 v = src[k * 9 * (SW / 4)];             // +18 float4 = 288 B/iter
        __builtin_nontemporal_store(v, &dst[k * NT]); // +576 float4 = 9 KB/iter
    }
}

extern "C" void kernel_launch(void* const* d_in, const int* in_sizes, int n_in,
                              void* d_out, int out_size, void* d_ws, size_t ws_size,
                              hipStream_t stream) {
    const f32x4* x4 = (const f32x4*)d_in[0];
    f32x4* out4 = (f32x4*)d_out;
    block_extract_strip<<<NBLOCKS, NT, 0, stream>>>(x4, out4);
}